// Round 8
// baseline (328.544 us; speedup 1.0000x reference)
//
#include <hip/hip_runtime.h>
#include <cmath>

// ---------------------------------------------------------------------------
// GCN 3-layer forward, MI355X — CSR-pull, ILP-unrolled CSR build.
//   g = (x@W) * dinv[row]
//   out[d] = elu?( dinv[d] * ( g[d] + sum_{s->d} g[s] ) + b )
// (identical to R6 submission — that round never ran: broker timeout)
// ---------------------------------------------------------------------------

__global__ __launch_bounds__(256) void k_zero_int(int* __restrict__ p, int n) {
    int i = blockIdx.x * 256 + threadIdx.x;
    if (i < n) p[i] = 0;
}

// histogram + per-edge rank; 8 edges/thread for atomic ILP
__global__ __launch_bounds__(256) void k_hist(const int* __restrict__ dst, int nE,
                                              int* __restrict__ cnt,
                                              int* __restrict__ rank) {
    const int t = blockIdx.x * 256 + threadIdx.x;
    const int e0 = t * 8;
    if (e0 + 8 <= nE) {
        int d[8], r[8];
#pragma unroll
        for (int i = 0; i < 8; ++i) d[i] = dst[e0 + i];      // -> 2x dwordx4
#pragma unroll
        for (int i = 0; i < 8; ++i) r[i] = atomicAdd(&cnt[d[i]], 1);
#pragma unroll
        for (int i = 0; i < 8; ++i) rank[e0 + i] = r[i];     // -> 2x dwordx4
    } else {
        for (int e = e0; e < nE; ++e) rank[e] = atomicAdd(&cnt[dst[e]], 1);
    }
}

// scan level 1: per-block (256-wide) sums of cnt
__global__ __launch_bounds__(256) void k_scan1(const int* __restrict__ cnt, int n,
                                               int* __restrict__ bsum) {
    __shared__ int s[256];
    int i = blockIdx.x * 256 + threadIdx.x;
    int v = (i < n) ? cnt[i] : 0;
    s[threadIdx.x] = v;
    __syncthreads();
    for (int off = 128; off > 0; off >>= 1) {
        if (threadIdx.x < off) s[threadIdx.x] += s[threadIdx.x + off];
        __syncthreads();
    }
    if (threadIdx.x == 0) bsum[blockIdx.x] = s[0];
}

// scan level 2: exclusive scan of block sums (nb <= 512), writes grand total
__global__ __launch_bounds__(512) void k_scan2(const int* __restrict__ bsum, int nb,
                                               int* __restrict__ boff,
                                               int* __restrict__ row_start, int n) {
    __shared__ int s[512];
    int v = (threadIdx.x < nb) ? bsum[threadIdx.x] : 0;
    s[threadIdx.x] = v;
    __syncthreads();
    for (int off = 1; off < 512; off <<= 1) {
        int t = (threadIdx.x >= off) ? s[threadIdx.x - off] : 0;
        __syncthreads();
        s[threadIdx.x] += t;
        __syncthreads();
    }
    if (threadIdx.x < nb) boff[threadIdx.x] = s[threadIdx.x] - v;  // exclusive
    if (threadIdx.x == nb - 1) row_start[n] = s[threadIdx.x];      // total
}

// scan level 3: per-block exclusive scan + block offset; also writes dinv.
__global__ __launch_bounds__(256) void k_scan3(const int* __restrict__ cnt, int n,
                                               const int* __restrict__ boff,
                                               int* __restrict__ row_start,
                                               float* __restrict__ dinv) {
    __shared__ int s[256];
    int i = blockIdx.x * 256 + threadIdx.x;
    int v = (i < n) ? cnt[i] : 0;
    s[threadIdx.x] = v;
    __syncthreads();
    for (int off = 1; off < 256; off <<= 1) {
        int t = (threadIdx.x >= off) ? s[threadIdx.x - off] : 0;
        __syncthreads();
        s[threadIdx.x] += t;
        __syncthreads();
    }
    if (i < n) {
        row_start[i] = boff[blockIdx.x] + s[threadIdx.x] - v;
        dinv[i] = rsqrtf((float)v + 1.0f);  // +1 self-loop
    }
}

// atomic-free CSR fill: slot = row_start[dst] + rank; 8 edges/thread for MLP
__global__ __launch_bounds__(256) void k_fill_csr(
    const int* __restrict__ src, const int* __restrict__ dst,
    const int* __restrict__ rank, const int* __restrict__ row_start,
    int nE, int* __restrict__ csr) {
    const int t = blockIdx.x * 256 + threadIdx.x;
    const int e0 = t * 8;
    if (e0 + 8 <= nE) {
        int d[8], r[8], s[8], slot[8];
#pragma unroll
        for (int i = 0; i < 8; ++i) d[i] = dst[e0 + i];
#pragma unroll
        for (int i = 0; i < 8; ++i) r[i] = rank[e0 + i];
#pragma unroll
        for (int i = 0; i < 8; ++i) s[i] = src[e0 + i];
#pragma unroll
        for (int i = 0; i < 8; ++i) slot[i] = row_start[d[i]];  // 8 gathers in flight
#pragma unroll
        for (int i = 0; i < 8; ++i) csr[slot[i] + r[i]] = s[i];
    } else {
        for (int e = e0; e < nE; ++e)
            csr[row_start[dst[e]] + rank[e]] = src[e];
    }
}

// LDS-staged register-blocked GEMM: [n x 64] @ [64 x OUT] -> g, rows * dinv.
// 256 threads; tile ROWS x OUT; thread = 4 rows x 4 cols accumulator.
template <int OUT>
__global__ __launch_bounds__(256) void k_gemm_scale(
    const float* __restrict__ x, const float* __restrict__ W,
    const float* __restrict__ dinv, float* __restrict__ g, int n) {
    constexpr int CG = OUT / 4;        // col-groups: 16 (OUT=64) / 8 (OUT=32)
    constexpr int RG = 256 / CG;       // row-groups: 16 / 32
    constexpr int ROWS = RG * 4;       // 64 / 128
    constexpr int XLD = 68;            // padded leading dim (floats)
    __shared__ float Ws[64 * OUT];
    __shared__ float xs[ROWS * XLD];

    const int tid = threadIdx.x;
    const int row0 = blockIdx.x * ROWS;

#pragma unroll
    for (int i = tid * 4; i < 64 * OUT; i += 1024)
        *reinterpret_cast<float4*>(&Ws[i]) =
            *reinterpret_cast<const float4*>(&W[i]);

#pragma unroll
    for (int it = 0; it < ROWS / 16; ++it) {
        const int flat = it * 1024 + tid * 4;   // float index in [ROWS*64]
        const int r = flat >> 6;
        const int k = flat & 63;
        float4 v;
        if (row0 + r < n)
            v = *reinterpret_cast<const float4*>(x + (size_t)(row0 + r) * 64 + k);
        else
            v = make_float4(0.f, 0.f, 0.f, 0.f);
        *reinterpret_cast<float4*>(&xs[r * XLD + k]) = v;
    }
    __syncthreads();

    const int rg = tid / CG;
    const int cg = tid % CG;
    const int r0 = rg * 4;

    float4 acc[4];
#pragma unroll
    for (int i = 0; i < 4; ++i) acc[i] = make_float4(0.f, 0.f, 0.f, 0.f);

#pragma unroll 2
    for (int kc = 0; kc < 16; ++kc) {           // K-chunks of 4
        float4 xr[4], wk[4];
#pragma unroll
        for (int i = 0; i < 4; ++i)
            xr[i] = *reinterpret_cast<const float4*>(&xs[(r0 + i) * XLD + kc * 4]);
#pragma unroll
        for (int kk = 0; kk < 4; ++kk)
            wk[kk] = *reinterpret_cast<const float4*>(&Ws[(kc * 4 + kk) * OUT + cg * 4]);
#pragma unroll
        for (int kk = 0; kk < 4; ++kk) {
#pragma unroll
            for (int i = 0; i < 4; ++i) {
                const float xv = (kk == 0) ? xr[i].x
                               : (kk == 1) ? xr[i].y
                               : (kk == 2) ? xr[i].z
                                           : xr[i].w;
                acc[i].x += xv * wk[kk].x;
                acc[i].y += xv * wk[kk].y;
                acc[i].z += xv * wk[kk].z;
                acc[i].w += xv * wk[kk].w;
            }
        }
    }

#pragma unroll
    for (int i = 0; i < 4; ++i) {
        const int row = row0 + r0 + i;
        if (row < n) {
            const float dv = dinv[row];
            float4 o;
            o.x = acc[i].x * dv;
            o.y = acc[i].y * dv;
            o.z = acc[i].z * dv;
            o.w = acc[i].w * dv;
            *reinterpret_cast<float4*>(g + (size_t)row * OUT + cg * 4) = o;
        }
    }
}

// Pull-aggregate + finalize: TPN = FEAT/4 threads per node, float4 rows.
// 4-way unrolled gather loop for memory-level parallelism.
template <int FEAT, bool ELU>
__global__ __launch_bounds__(256) void k_aggregate(
    const float* __restrict__ g, const int* __restrict__ row_start,
    const int* __restrict__ csr, const float* __restrict__ dinv,
    const float* __restrict__ b, float* __restrict__ out, int n) {
    constexpr int TPN = FEAT / 4;
    constexpr int NPB = 256 / TPN;
    const int tid = threadIdx.x;
    const int node = blockIdx.x * NPB + tid / TPN;
    const int sub = tid % TPN;
    if (node >= n) return;

    const int r0 = row_start[node];
    const int r1 = row_start[node + 1];
    float4 acc = *reinterpret_cast<const float4*>(g + (size_t)node * FEAT + sub * 4);

    int j = r0;
    for (; j + 4 <= r1; j += 4) {
        int s0 = csr[j], s1 = csr[j + 1], s2 = csr[j + 2], s3 = csr[j + 3];
        float4 v0 = *reinterpret_cast<const float4*>(g + (size_t)s0 * FEAT + sub * 4);
        float4 v1 = *reinterpret_cast<const float4*>(g + (size_t)s1 * FEAT + sub * 4);
        float4 v2 = *reinterpret_cast<const float4*>(g + (size_t)s2 * FEAT + sub * 4);
        float4 v3 = *reinterpret_cast<const float4*>(g + (size_t)s3 * FEAT + sub * 4);
        acc.x += v0.x + v1.x + v2.x + v3.x;
        acc.y += v0.y + v1.y + v2.y + v3.y;
        acc.z += v0.z + v1.z + v2.z + v3.z;
        acc.w += v0.w + v1.w + v2.w + v3.w;
    }
    for (; j < r1; ++j) {
        int s = csr[j];
        float4 v = *reinterpret_cast<const float4*>(g + (size_t)s * FEAT + sub * 4);
        acc.x += v.x; acc.y += v.y; acc.z += v.z; acc.w += v.w;
    }

    const float dv = dinv[node];
    const float4 bb = *reinterpret_cast<const float4*>(b + sub * 4);
    float4 o;
    o.x = dv * acc.x + bb.x;
    o.y = dv * acc.y + bb.y;
    o.z = dv * acc.z + bb.z;
    o.w = dv * acc.w + bb.w;
    if (ELU) {
        o.x = o.x > 0.f ? o.x : expm1f(o.x);
        o.y = o.y > 0.f ? o.y : expm1f(o.y);
        o.z = o.z > 0.f ? o.z : expm1f(o.z);
        o.w = o.w > 0.f ? o.w : expm1f(o.w);
    }
    *reinterpret_cast<float4*>(out + (size_t)node * FEAT + sub * 4) = o;
}

extern "C" void kernel_launch(void* const* d_in, const int* in_sizes, int n_in,
                              void* d_out, int out_size, void* d_ws, size_t ws_size,
                              hipStream_t stream) {
    const float* x  = (const float*)d_in[0];
    const float* W1 = (const float*)d_in[1];
    const float* b1 = (const float*)d_in[2];
    const float* W2 = (const float*)d_in[3];
    const float* b2 = (const float*)d_in[4];
    const float* W3 = (const float*)d_in[5];
    const float* b3 = (const float*)d_in[6];
    const int*   ei = (const int*)d_in[7];     // int32 (JAX x64-disabled)

    const int N  = in_sizes[0] / 64;           // 80000
    const int E  = in_sizes[7] / 2;            // 1280000
    const int* src = ei;
    const int* dst = ei + E;

    auto cdiv = [](long long a, long long b) { return (int)((a + b - 1) / b); };
    const int NB = cdiv(N, 256);               // scan blocks (313)

    // workspace layout
    float* ws = (float*)d_ws;
    float* dinv = ws;                           // [N]
    float* A    = dinv + N;                     // [N*64]  g buffer
    float* C    = A + (size_t)N * 64;           // [N*64]  layer output
    int* cnt       = (int*)(C + (size_t)N * 64);// [N]
    int* row_start = cnt + N;                   // [N+1]
    int* csr       = row_start + N + 1;         // [E]
    int* bsum      = csr + E;                   // [NB]
    int* boff      = bsum + NB;                 // [NB]
    int* rank      = (int*)C;                   // [E] aliases C (free until layer-1 agg)
    float* out = (float*)d_out;                 // [N*32]

    // --- CSR build + dinv (once per call) ---
    k_zero_int<<<NB, 256, 0, stream>>>(cnt, N);
    k_hist<<<cdiv(E, 2048), 256, 0, stream>>>(dst, E, cnt, rank);
    k_scan1<<<NB, 256, 0, stream>>>(cnt, N, bsum);
    k_scan2<<<1, 512, 0, stream>>>(bsum, NB, boff, row_start, N);
    k_scan3<<<NB, 256, 0, stream>>>(cnt, N, boff, row_start, dinv);
    k_fill_csr<<<cdiv(E, 2048), 256, 0, stream>>>(src, dst, rank, row_start, E, csr);

    // --- layer 1: x -> C ---
    k_gemm_scale<64><<<cdiv(N, 64), 256, 0, stream>>>(x, W1, dinv, A, N);
    k_aggregate<64, true><<<cdiv(N, 16), 256, 0, stream>>>(A, row_start, csr, dinv, b1, C, N);

    // --- layer 2: C -> C (A as intermediate g) ---
    k_gemm_scale<64><<<cdiv(N, 64), 256, 0, stream>>>(C, W2, dinv, A, N);
    k_aggregate<64, true><<<cdiv(N, 16), 256, 0, stream>>>(A, row_start, csr, dinv, b2, C, N);

    // --- layer 3: C -> d_out ---
    k_gemm_scale<32><<<cdiv(N, 128), 256, 0, stream>>>(C, W3, dinv, A, N);
    k_aggregate<32, false><<<cdiv(N, 32), 256, 0, stream>>>(A, row_start, csr, dinv, b3, out, N);
}

// Round 9
// 326.221 us; speedup vs baseline: 1.0071x; 1.0071x over previous
//
#include <hip/hip_runtime.h>
#include <cmath>

// ---------------------------------------------------------------------------
// GCN 3-layer forward, MI355X — CSR-pull; 4-way sharded histogram CSR build.
//   g = (x@W) * dinv[row]
//   out[d] = elu?( dinv[d] * ( g[d] + sum_{s->d} g[s] ) + b )
// rank packed as (shard<<28)|local_rank; slot = base4[d][shard] + local_rank.
// ---------------------------------------------------------------------------

__global__ __launch_bounds__(256) void k_zero_int(int* __restrict__ p, int n) {
    int i = blockIdx.x * 256 + threadIdx.x;
    if (i < n) p[i] = 0;
}

// sharded histogram + packed per-edge rank; 4 edges/thread (int4 loads)
__global__ __launch_bounds__(256) void k_hist(const int* __restrict__ dst, int nE,
                                              int nN, int* __restrict__ cnt4,
                                              int* __restrict__ rankp) {
    const int t = blockIdx.x * 256 + threadIdx.x;
    const int e0 = t * 4;
    const int sh = (threadIdx.x >> 6) & 3;       // per-wave shard
    int* __restrict__ mycnt = cnt4 + (size_t)sh * nN;
    if (e0 + 4 <= nE) {
        int4 d = *reinterpret_cast<const int4*>(dst + e0);
        int r0 = atomicAdd(&mycnt[d.x], 1);
        int r1 = atomicAdd(&mycnt[d.y], 1);
        int r2 = atomicAdd(&mycnt[d.z], 1);
        int r3 = atomicAdd(&mycnt[d.w], 1);
        int4 rp = make_int4(r0 | (sh << 28), r1 | (sh << 28),
                            r2 | (sh << 28), r3 | (sh << 28));
        *reinterpret_cast<int4*>(rankp + e0) = rp;
    } else {
        for (int e = e0; e < nE; ++e)
            rankp[e] = atomicAdd(&mycnt[dst[e]], 1) | (sh << 28);
    }
}

// scan level 1: per-block (256-wide) sums over all 4 shards
__global__ __launch_bounds__(256) void k_scan1(const int* __restrict__ cnt4, int n,
                                               int* __restrict__ bsum) {
    __shared__ int s[256];
    int i = blockIdx.x * 256 + threadIdx.x;
    int v = 0;
    if (i < n)
        v = cnt4[i] + cnt4[n + i] + cnt4[2 * n + i] + cnt4[3 * n + i];
    s[threadIdx.x] = v;
    __syncthreads();
    for (int off = 128; off > 0; off >>= 1) {
        if (threadIdx.x < off) s[threadIdx.x] += s[threadIdx.x + off];
        __syncthreads();
    }
    if (threadIdx.x == 0) bsum[blockIdx.x] = s[0];
}

// scan level 2: exclusive scan of block sums (nb <= 512), writes grand total
__global__ __launch_bounds__(512) void k_scan2(const int* __restrict__ bsum, int nb,
                                               int* __restrict__ boff,
                                               int* __restrict__ row_start, int n) {
    __shared__ int s[512];
    int v = (threadIdx.x < nb) ? bsum[threadIdx.x] : 0;
    s[threadIdx.x] = v;
    __syncthreads();
    for (int off = 1; off < 512; off <<= 1) {
        int t = (threadIdx.x >= off) ? s[threadIdx.x - off] : 0;
        __syncthreads();
        s[threadIdx.x] += t;
        __syncthreads();
    }
    if (threadIdx.x < nb) boff[threadIdx.x] = s[threadIdx.x] - v;  // exclusive
    if (threadIdx.x == nb - 1) row_start[n] = s[threadIdx.x];      // total
}

// scan level 3: per-block exclusive scan of node totals + block offset;
// writes row_start, dinv, and per-node shard bases base4[d] = rs + prefix.
__global__ __launch_bounds__(256) void k_scan3(const int* __restrict__ cnt4, int n,
                                               const int* __restrict__ boff,
                                               int* __restrict__ row_start,
                                               int4* __restrict__ base4,
                                               float* __restrict__ dinv) {
    __shared__ int s[256];
    int i = blockIdx.x * 256 + threadIdx.x;
    int c0 = 0, c1 = 0, c2 = 0, c3 = 0;
    if (i < n) {
        c0 = cnt4[i];
        c1 = cnt4[n + i];
        c2 = cnt4[2 * n + i];
        c3 = cnt4[3 * n + i];
    }
    const int v = c0 + c1 + c2 + c3;
    s[threadIdx.x] = v;
    __syncthreads();
    for (int off = 1; off < 256; off <<= 1) {
        int t = (threadIdx.x >= off) ? s[threadIdx.x - off] : 0;
        __syncthreads();
        s[threadIdx.x] += t;
        __syncthreads();
    }
    if (i < n) {
        const int ex = boff[blockIdx.x] + s[threadIdx.x] - v;
        row_start[i] = ex;
        base4[i] = make_int4(ex, ex + c0, ex + c0 + c1, ex + c0 + c1 + c2);
        dinv[i] = rsqrtf((float)v + 1.0f);  // +1 self-loop
    }
}

// atomic-free CSR fill: slot = base4[dst][shard] + local_rank; 4 edges/thread
__global__ __launch_bounds__(256) void k_fill_csr(
    const int* __restrict__ src, const int* __restrict__ dst,
    const int* __restrict__ rankp, const int4* __restrict__ base4,
    int nE, int* __restrict__ csr) {
    const int t = blockIdx.x * 256 + threadIdx.x;
    const int e0 = t * 4;
    if (e0 + 4 <= nE) {
        int4 d = *reinterpret_cast<const int4*>(dst + e0);
        int4 s = *reinterpret_cast<const int4*>(src + e0);
        int4 rp = *reinterpret_cast<const int4*>(rankp + e0);
        int4 b0 = base4[d.x];
        int4 b1 = base4[d.y];
        int4 b2 = base4[d.z];
        int4 b3 = base4[d.w];
        auto pick = [](const int4& b, int sh) {
            return sh == 0 ? b.x : sh == 1 ? b.y : sh == 2 ? b.z : b.w;
        };
        csr[pick(b0, rp.x >> 28) + (rp.x & 0x0FFFFFFF)] = s.x;
        csr[pick(b1, rp.y >> 28) + (rp.y & 0x0FFFFFFF)] = s.y;
        csr[pick(b2, rp.z >> 28) + (rp.z & 0x0FFFFFFF)] = s.z;
        csr[pick(b3, rp.w >> 28) + (rp.w & 0x0FFFFFFF)] = s.w;
    } else {
        for (int e = e0; e < nE; ++e) {
            int rp = rankp[e];
            int4 b = base4[dst[e]];
            int sh = rp >> 28;
            int base = sh == 0 ? b.x : sh == 1 ? b.y : sh == 2 ? b.z : b.w;
            csr[base + (rp & 0x0FFFFFFF)] = src[e];
        }
    }
}

// LDS-staged register-blocked GEMM: [n x 64] @ [64 x OUT] -> g, rows * dinv.
template <int OUT>
__global__ __launch_bounds__(256) void k_gemm_scale(
    const float* __restrict__ x, const float* __restrict__ W,
    const float* __restrict__ dinv, float* __restrict__ g, int n) {
    constexpr int CG = OUT / 4;        // col-groups: 16 (OUT=64) / 8 (OUT=32)
    constexpr int RG = 256 / CG;       // row-groups: 16 / 32
    constexpr int ROWS = RG * 4;       // 64 / 128
    constexpr int XLD = 68;            // padded leading dim (floats)
    __shared__ float Ws[64 * OUT];
    __shared__ float xs[ROWS * XLD];

    const int tid = threadIdx.x;
    const int row0 = blockIdx.x * ROWS;

#pragma unroll
    for (int i = tid * 4; i < 64 * OUT; i += 1024)
        *reinterpret_cast<float4*>(&Ws[i]) =
            *reinterpret_cast<const float4*>(&W[i]);

#pragma unroll
    for (int it = 0; it < ROWS / 16; ++it) {
        const int flat = it * 1024 + tid * 4;   // float index in [ROWS*64]
        const int r = flat >> 6;
        const int k = flat & 63;
        float4 v;
        if (row0 + r < n)
            v = *reinterpret_cast<const float4*>(x + (size_t)(row0 + r) * 64 + k);
        else
            v = make_float4(0.f, 0.f, 0.f, 0.f);
        *reinterpret_cast<float4*>(&xs[r * XLD + k]) = v;
    }
    __syncthreads();

    const int rg = tid / CG;
    const int cg = tid % CG;
    const int r0 = rg * 4;

    float4 acc[4];
#pragma unroll
    for (int i = 0; i < 4; ++i) acc[i] = make_float4(0.f, 0.f, 0.f, 0.f);

#pragma unroll 2
    for (int kc = 0; kc < 16; ++kc) {           // K-chunks of 4
        float4 xr[4], wk[4];
#pragma unroll
        for (int i = 0; i < 4; ++i)
            xr[i] = *reinterpret_cast<const float4*>(&xs[(r0 + i) * XLD + kc * 4]);
#pragma unroll
        for (int kk = 0; kk < 4; ++kk)
            wk[kk] = *reinterpret_cast<const float4*>(&Ws[(kc * 4 + kk) * OUT + cg * 4]);
#pragma unroll
        for (int kk = 0; kk < 4; ++kk) {
#pragma unroll
            for (int i = 0; i < 4; ++i) {
                const float xv = (kk == 0) ? xr[i].x
                               : (kk == 1) ? xr[i].y
                               : (kk == 2) ? xr[i].z
                                           : xr[i].w;
                acc[i].x += xv * wk[kk].x;
                acc[i].y += xv * wk[kk].y;
                acc[i].z += xv * wk[kk].z;
                acc[i].w += xv * wk[kk].w;
            }
        }
    }

#pragma unroll
    for (int i = 0; i < 4; ++i) {
        const int row = row0 + r0 + i;
        if (row < n) {
            const float dv = dinv[row];
            float4 o;
            o.x = acc[i].x * dv;
            o.y = acc[i].y * dv;
            o.z = acc[i].z * dv;
            o.w = acc[i].w * dv;
            *reinterpret_cast<float4*>(g + (size_t)row * OUT + cg * 4) = o;
        }
    }
}

// Pull-aggregate + finalize: TPN = FEAT/4 threads per node, float4 rows.
template <int FEAT, bool ELU>
__global__ __launch_bounds__(256) void k_aggregate(
    const float* __restrict__ g, const int* __restrict__ row_start,
    const int* __restrict__ csr, const float* __restrict__ dinv,
    const float* __restrict__ b, float* __restrict__ out, int n) {
    constexpr int TPN = FEAT / 4;
    constexpr int NPB = 256 / TPN;
    const int tid = threadIdx.x;
    const int node = blockIdx.x * NPB + tid / TPN;
    const int sub = tid % TPN;
    if (node >= n) return;

    const int r0 = row_start[node];
    const int r1 = row_start[node + 1];
    float4 acc = *reinterpret_cast<const float4*>(g + (size_t)node * FEAT + sub * 4);

    int j = r0;
    for (; j + 4 <= r1; j += 4) {
        int s0 = csr[j], s1 = csr[j + 1], s2 = csr[j + 2], s3 = csr[j + 3];
        float4 v0 = *reinterpret_cast<const float4*>(g + (size_t)s0 * FEAT + sub * 4);
        float4 v1 = *reinterpret_cast<const float4*>(g + (size_t)s1 * FEAT + sub * 4);
        float4 v2 = *reinterpret_cast<const float4*>(g + (size_t)s2 * FEAT + sub * 4);
        float4 v3 = *reinterpret_cast<const float4*>(g + (size_t)s3 * FEAT + sub * 4);
        acc.x += v0.x + v1.x + v2.x + v3.x;
        acc.y += v0.y + v1.y + v2.y + v3.y;
        acc.z += v0.z + v1.z + v2.z + v3.z;
        acc.w += v0.w + v1.w + v2.w + v3.w;
    }
    for (; j < r1; ++j) {
        int s = csr[j];
        float4 v = *reinterpret_cast<const float4*>(g + (size_t)s * FEAT + sub * 4);
        acc.x += v.x; acc.y += v.y; acc.z += v.z; acc.w += v.w;
    }

    const float dv = dinv[node];
    const float4 bb = *reinterpret_cast<const float4*>(b + sub * 4);
    float4 o;
    o.x = dv * acc.x + bb.x;
    o.y = dv * acc.y + bb.y;
    o.z = dv * acc.z + bb.z;
    o.w = dv * acc.w + bb.w;
    if (ELU) {
        o.x = o.x > 0.f ? o.x : expm1f(o.x);
        o.y = o.y > 0.f ? o.y : expm1f(o.y);
        o.z = o.z > 0.f ? o.z : expm1f(o.z);
        o.w = o.w > 0.f ? o.w : expm1f(o.w);
    }
    *reinterpret_cast<float4*>(out + (size_t)node * FEAT + sub * 4) = o;
}

extern "C" void kernel_launch(void* const* d_in, const int* in_sizes, int n_in,
                              void* d_out, int out_size, void* d_ws, size_t ws_size,
                              hipStream_t stream) {
    const float* x  = (const float*)d_in[0];
    const float* W1 = (const float*)d_in[1];
    const float* b1 = (const float*)d_in[2];
    const float* W2 = (const float*)d_in[3];
    const float* b2 = (const float*)d_in[4];
    const float* W3 = (const float*)d_in[5];
    const float* b3 = (const float*)d_in[6];
    const int*   ei = (const int*)d_in[7];     // int32 (JAX x64-disabled)

    const int N  = in_sizes[0] / 64;           // 80000
    const int E  = in_sizes[7] / 2;            // 1280000
    const int* src = ei;
    const int* dst = ei + E;

    auto cdiv = [](long long a, long long b) { return (int)((a + b - 1) / b); };
    const int NB = cdiv(N, 256);               // scan blocks (313)

    // workspace layout (16B-aligned chunks first)
    float* ws = (float*)d_ws;
    float* dinv = ws;                           // [N]
    float* A    = dinv + N;                     // [N*64]  g buffer
    float* C    = A + (size_t)N * 64;           // [N*64]  layer output
    int* cnt4      = (int*)(C + (size_t)N * 64);// [4*N]  sharded histogram
    int4* base4    = (int4*)(cnt4 + 4 * (size_t)N); // [N] (16B-aligned: 129N,4N mult of 4)
    int* row_start = (int*)(base4 + N);         // [N+1]
    int* csr       = row_start + N + 1;         // [E]
    int* bsum      = csr + E;                   // [NB]
    int* boff      = bsum + NB;                 // [NB]
    int* rankp     = (int*)C;                   // [E] aliases C (free until layer-1 agg)
    float* out = (float*)d_out;                 // [N*32]

    // --- CSR build + dinv (once per call) ---
    k_zero_int<<<cdiv(4 * (long long)N, 256), 256, 0, stream>>>(cnt4, 4 * N);
    k_hist<<<cdiv(E, 1024), 256, 0, stream>>>(dst, E, N, cnt4, rankp);
    k_scan1<<<NB, 256, 0, stream>>>(cnt4, N, bsum);
    k_scan2<<<1, 512, 0, stream>>>(bsum, NB, boff, row_start, N);
    k_scan3<<<NB, 256, 0, stream>>>(cnt4, N, boff, row_start, base4, dinv);
    k_fill_csr<<<cdiv(E, 1024), 256, 0, stream>>>(src, dst, rankp, base4, E, csr);

    // --- layer 1: x -> C ---
    k_gemm_scale<64><<<cdiv(N, 64), 256, 0, stream>>>(x, W1, dinv, A, N);
    k_aggregate<64, true><<<cdiv(N, 16), 256, 0, stream>>>(A, row_start, csr, dinv, b1, C, N);

    // --- layer 2: C -> C (A as intermediate g) ---
    k_gemm_scale<64><<<cdiv(N, 64), 256, 0, stream>>>(C, W2, dinv, A, N);
    k_aggregate<64, true><<<cdiv(N, 16), 256, 0, stream>>>(A, row_start, csr, dinv, b2, C, N);

    // --- layer 3: C -> d_out ---
    k_gemm_scale<32><<<cdiv(N, 128), 256, 0, stream>>>(C, W3, dinv, A, N);
    k_aggregate<32, false><<<cdiv(N, 32), 256, 0, stream>>>(A, row_start, csr, dinv, b3, out, N);
}

// Round 10
// 312.867 us; speedup vs baseline: 1.0501x; 1.0427x over previous
//
#include <hip/hip_runtime.h>
#include <cmath>

// ---------------------------------------------------------------------------
// GCN 3-layer forward, MI355X — CSR-pull; hist fused with GEMM1 (independent).
//   h1 = x@W1 (unscaled, fused with hist);  layer1 agg applies dinv[s]*dinv[d]
//   g2,g3 = (h@W)*dinv[row];  out[d] = elu?( dinv[d]*(g[d]+sum g[s]) + b )
// Returning-atomic ceiling (~22G/s) makes hist ~53us regardless of occupancy/
// contention (R8/R9 evidence) -> hide it under GEMM1 instead of shrinking it.
// ---------------------------------------------------------------------------

// ---- fused: odd blocks = sharded histogram, even blocks = GEMM1 (unscaled) --
__global__ __launch_bounds__(256) void k_hist_gemm1(
    const int* __restrict__ dst, int nE, int nN,
    int* __restrict__ cnt4, int* __restrict__ rankp,
    const float* __restrict__ x, const float* __restrict__ W,
    float* __restrict__ h, int n) {
    constexpr int OUT = 64;
    constexpr int CG = OUT / 4;        // 16 col-groups
    constexpr int RG = 256 / CG;       // 16 row-groups
    constexpr int ROWS = RG * 4;       // 64 rows/block
    constexpr int XLD = 68;
    __shared__ float Ws[64 * OUT];
    __shared__ float xs[ROWS * XLD];

    const int tid = threadIdx.x;

    if (blockIdx.x & 1) {
        // ---------------- histogram + packed rank (4 edges/thread) ----------
        const int bid = blockIdx.x >> 1;
        const int t = bid * 256 + tid;
        const int e0 = t * 4;
        const int sh = (tid >> 6) & 3;                 // per-wave shard
        int* __restrict__ mycnt = cnt4 + (size_t)sh * nN;
        if (e0 + 4 <= nE) {
            int4 d = *reinterpret_cast<const int4*>(dst + e0);
            int r0 = atomicAdd(&mycnt[d.x], 1);
            int r1 = atomicAdd(&mycnt[d.y], 1);
            int r2 = atomicAdd(&mycnt[d.z], 1);
            int r3 = atomicAdd(&mycnt[d.w], 1);
            *reinterpret_cast<int4*>(rankp + e0) =
                make_int4(r0 | (sh << 28), r1 | (sh << 28),
                          r2 | (sh << 28), r3 | (sh << 28));
        } else {
            for (int e = e0; e < nE; ++e)
                rankp[e] = atomicAdd(&mycnt[dst[e]], 1) | (sh << 28);
        }
        return;
    }

    // ---------------- GEMM1: h = x @ W (64x64), no dinv scaling -------------
    const int bid = blockIdx.x >> 1;
    const int row0 = bid * ROWS;

#pragma unroll
    for (int i = tid * 4; i < 64 * OUT; i += 1024)
        *reinterpret_cast<float4*>(&Ws[i]) =
            *reinterpret_cast<const float4*>(&W[i]);

#pragma unroll
    for (int it = 0; it < ROWS / 16; ++it) {
        const int flat = it * 1024 + tid * 4;
        const int r = flat >> 6;
        const int k = flat & 63;
        float4 v;
        if (row0 + r < n)
            v = *reinterpret_cast<const float4*>(x + (size_t)(row0 + r) * 64 + k);
        else
            v = make_float4(0.f, 0.f, 0.f, 0.f);
        *reinterpret_cast<float4*>(&xs[r * XLD + k]) = v;
    }
    __syncthreads();

    const int rg = tid / CG;
    const int cg = tid % CG;
    const int r0 = rg * 4;

    float4 acc[4];
#pragma unroll
    for (int i = 0; i < 4; ++i) acc[i] = make_float4(0.f, 0.f, 0.f, 0.f);

#pragma unroll 2
    for (int kc = 0; kc < 16; ++kc) {
        float4 xr[4], wk[4];
#pragma unroll
        for (int i = 0; i < 4; ++i)
            xr[i] = *reinterpret_cast<const float4*>(&xs[(r0 + i) * XLD + kc * 4]);
#pragma unroll
        for (int kk = 0; kk < 4; ++kk)
            wk[kk] = *reinterpret_cast<const float4*>(&Ws[(kc * 4 + kk) * OUT + cg * 4]);
#pragma unroll
        for (int kk = 0; kk < 4; ++kk) {
#pragma unroll
            for (int i = 0; i < 4; ++i) {
                const float xv = (kk == 0) ? xr[i].x
                               : (kk == 1) ? xr[i].y
                               : (kk == 2) ? xr[i].z
                                           : xr[i].w;
                acc[i].x += xv * wk[kk].x;
                acc[i].y += xv * wk[kk].y;
                acc[i].z += xv * wk[kk].z;
                acc[i].w += xv * wk[kk].w;
            }
        }
    }

#pragma unroll
    for (int i = 0; i < 4; ++i) {
        const int row = row0 + r0 + i;
        if (row < n)
            *reinterpret_cast<float4*>(h + (size_t)row * OUT + cg * 4) = acc[i];
    }
}

// scan level 1: per-block (256-wide) sums over all 4 shards
__global__ __launch_bounds__(256) void k_scan1(const int* __restrict__ cnt4, int n,
                                               int* __restrict__ bsum) {
    __shared__ int s[256];
    int i = blockIdx.x * 256 + threadIdx.x;
    int v = 0;
    if (i < n)
        v = cnt4[i] + cnt4[n + i] + cnt4[2 * n + i] + cnt4[3 * n + i];
    s[threadIdx.x] = v;
    __syncthreads();
    for (int off = 128; off > 0; off >>= 1) {
        if (threadIdx.x < off) s[threadIdx.x] += s[threadIdx.x + off];
        __syncthreads();
    }
    if (threadIdx.x == 0) bsum[blockIdx.x] = s[0];
}

// scan level 2: exclusive scan of block sums (nb <= 512), writes grand total
__global__ __launch_bounds__(512) void k_scan2(const int* __restrict__ bsum, int nb,
                                               int* __restrict__ boff,
                                               int* __restrict__ row_start, int n) {
    __shared__ int s[512];
    int v = (threadIdx.x < nb) ? bsum[threadIdx.x] : 0;
    s[threadIdx.x] = v;
    __syncthreads();
    for (int off = 1; off < 512; off <<= 1) {
        int t = (threadIdx.x >= off) ? s[threadIdx.x - off] : 0;
        __syncthreads();
        s[threadIdx.x] += t;
        __syncthreads();
    }
    if (threadIdx.x < nb) boff[threadIdx.x] = s[threadIdx.x] - v;  // exclusive
    if (threadIdx.x == nb - 1) row_start[n] = s[threadIdx.x];      // total
}

// scan level 3: exclusive scan + block offset; writes row_start, base4, dinv.
__global__ __launch_bounds__(256) void k_scan3(const int* __restrict__ cnt4, int n,
                                               const int* __restrict__ boff,
                                               int* __restrict__ row_start,
                                               int4* __restrict__ base4,
                                               float* __restrict__ dinv) {
    __shared__ int s[256];
    int i = blockIdx.x * 256 + threadIdx.x;
    int c0 = 0, c1 = 0, c2 = 0, c3 = 0;
    if (i < n) {
        c0 = cnt4[i];
        c1 = cnt4[n + i];
        c2 = cnt4[2 * n + i];
        c3 = cnt4[3 * n + i];
    }
    const int v = c0 + c1 + c2 + c3;
    s[threadIdx.x] = v;
    __syncthreads();
    for (int off = 1; off < 256; off <<= 1) {
        int t = (threadIdx.x >= off) ? s[threadIdx.x - off] : 0;
        __syncthreads();
        s[threadIdx.x] += t;
        __syncthreads();
    }
    if (i < n) {
        const int ex = boff[blockIdx.x] + s[threadIdx.x] - v;
        row_start[i] = ex;
        base4[i] = make_int4(ex, ex + c0, ex + c0 + c1, ex + c0 + c1 + c2);
        dinv[i] = rsqrtf((float)v + 1.0f);  // +1 self-loop
    }
}

// atomic-free CSR fill: slot = base4[dst][shard] + local_rank; 4 edges/thread
__global__ __launch_bounds__(256) void k_fill_csr(
    const int* __restrict__ src, const int* __restrict__ dst,
    const int* __restrict__ rankp, const int4* __restrict__ base4,
    int nE, int* __restrict__ csr) {
    const int t = blockIdx.x * 256 + threadIdx.x;
    const int e0 = t * 4;
    if (e0 + 4 <= nE) {
        int4 d = *reinterpret_cast<const int4*>(dst + e0);
        int4 s = *reinterpret_cast<const int4*>(src + e0);
        int4 rp = *reinterpret_cast<const int4*>(rankp + e0);
        int4 b0 = base4[d.x];
        int4 b1 = base4[d.y];
        int4 b2 = base4[d.z];
        int4 b3 = base4[d.w];
        auto pick = [](const int4& b, int sh) {
            return sh == 0 ? b.x : sh == 1 ? b.y : sh == 2 ? b.z : b.w;
        };
        csr[pick(b0, rp.x >> 28) + (rp.x & 0x0FFFFFFF)] = s.x;
        csr[pick(b1, rp.y >> 28) + (rp.y & 0x0FFFFFFF)] = s.y;
        csr[pick(b2, rp.z >> 28) + (rp.z & 0x0FFFFFFF)] = s.z;
        csr[pick(b3, rp.w >> 28) + (rp.w & 0x0FFFFFFF)] = s.w;
    } else {
        for (int e = e0; e < nE; ++e) {
            int rp = rankp[e];
            int4 b = base4[dst[e]];
            int sh = rp >> 28;
            int base = sh == 0 ? b.x : sh == 1 ? b.y : sh == 2 ? b.z : b.w;
            csr[base + (rp & 0x0FFFFFFF)] = src[e];
        }
    }
}

// LDS-staged register-blocked GEMM: [n x 64] @ [64 x OUT] -> g, rows * dinv.
template <int OUT>
__global__ __launch_bounds__(256) void k_gemm_scale(
    const float* __restrict__ x, const float* __restrict__ W,
    const float* __restrict__ dinv, float* __restrict__ g, int n) {
    constexpr int CG = OUT / 4;
    constexpr int RG = 256 / CG;
    constexpr int ROWS = RG * 4;
    constexpr int XLD = 68;
    __shared__ float Ws[64 * OUT];
    __shared__ float xs[ROWS * XLD];

    const int tid = threadIdx.x;
    const int row0 = blockIdx.x * ROWS;

#pragma unroll
    for (int i = tid * 4; i < 64 * OUT; i += 1024)
        *reinterpret_cast<float4*>(&Ws[i]) =
            *reinterpret_cast<const float4*>(&W[i]);

#pragma unroll
    for (int it = 0; it < ROWS / 16; ++it) {
        const int flat = it * 1024 + tid * 4;
        const int r = flat >> 6;
        const int k = flat & 63;
        float4 v;
        if (row0 + r < n)
            v = *reinterpret_cast<const float4*>(x + (size_t)(row0 + r) * 64 + k);
        else
            v = make_float4(0.f, 0.f, 0.f, 0.f);
        *reinterpret_cast<float4*>(&xs[r * XLD + k]) = v;
    }
    __syncthreads();

    const int rg = tid / CG;
    const int cg = tid % CG;
    const int r0 = rg * 4;

    float4 acc[4];
#pragma unroll
    for (int i = 0; i < 4; ++i) acc[i] = make_float4(0.f, 0.f, 0.f, 0.f);

#pragma unroll 2
    for (int kc = 0; kc < 16; ++kc) {
        float4 xr[4], wk[4];
#pragma unroll
        for (int i = 0; i < 4; ++i)
            xr[i] = *reinterpret_cast<const float4*>(&xs[(r0 + i) * XLD + kc * 4]);
#pragma unroll
        for (int kk = 0; kk < 4; ++kk)
            wk[kk] = *reinterpret_cast<const float4*>(&Ws[(kc * 4 + kk) * OUT + cg * 4]);
#pragma unroll
        for (int kk = 0; kk < 4; ++kk) {
#pragma unroll
            for (int i = 0; i < 4; ++i) {
                const float xv = (kk == 0) ? xr[i].x
                               : (kk == 1) ? xr[i].y
                               : (kk == 2) ? xr[i].z
                                           : xr[i].w;
                acc[i].x += xv * wk[kk].x;
                acc[i].y += xv * wk[kk].y;
                acc[i].z += xv * wk[kk].z;
                acc[i].w += xv * wk[kk].w;
            }
        }
    }

#pragma unroll
    for (int i = 0; i < 4; ++i) {
        const int row = row0 + r0 + i;
        if (row < n) {
            const float dv = dinv[row];
            float4 o;
            o.x = acc[i].x * dv;
            o.y = acc[i].y * dv;
            o.z = acc[i].z * dv;
            o.w = acc[i].w * dv;
            *reinterpret_cast<float4*>(g + (size_t)row * OUT + cg * 4) = o;
        }
    }
}

// Pull-aggregate + finalize. SCALE_SRC: g holds unscaled h -> multiply each
// gathered row (and the self row) by dinv[src] on the fly (L2-resident).
template <int FEAT, bool ELU, bool SCALE_SRC>
__global__ __launch_bounds__(256) void k_aggregate(
    const float* __restrict__ g, const int* __restrict__ row_start,
    const int* __restrict__ csr, const float* __restrict__ dinv,
    const float* __restrict__ b, float* __restrict__ out, int n) {
    constexpr int TPN = FEAT / 4;
    constexpr int NPB = 256 / TPN;
    const int tid = threadIdx.x;
    const int node = blockIdx.x * NPB + tid / TPN;
    const int sub = tid % TPN;
    if (node >= n) return;

    const int r0 = row_start[node];
    const int r1 = row_start[node + 1];
    const float dv = dinv[node];

    float4 acc = *reinterpret_cast<const float4*>(g + (size_t)node * FEAT + sub * 4);
    if (SCALE_SRC) { acc.x *= dv; acc.y *= dv; acc.z *= dv; acc.w *= dv; }

    int j = r0;
    for (; j + 4 <= r1; j += 4) {
        int s0 = csr[j], s1 = csr[j + 1], s2 = csr[j + 2], s3 = csr[j + 3];
        float4 v0 = *reinterpret_cast<const float4*>(g + (size_t)s0 * FEAT + sub * 4);
        float4 v1 = *reinterpret_cast<const float4*>(g + (size_t)s1 * FEAT + sub * 4);
        float4 v2 = *reinterpret_cast<const float4*>(g + (size_t)s2 * FEAT + sub * 4);
        float4 v3 = *reinterpret_cast<const float4*>(g + (size_t)s3 * FEAT + sub * 4);
        if (SCALE_SRC) {
            float w0 = dinv[s0], w1 = dinv[s1], w2 = dinv[s2], w3 = dinv[s3];
            acc.x += w0 * v0.x + w1 * v1.x + w2 * v2.x + w3 * v3.x;
            acc.y += w0 * v0.y + w1 * v1.y + w2 * v2.y + w3 * v3.y;
            acc.z += w0 * v0.z + w1 * v1.z + w2 * v2.z + w3 * v3.z;
            acc.w += w0 * v0.w + w1 * v1.w + w2 * v2.w + w3 * v3.w;
        } else {
            acc.x += v0.x + v1.x + v2.x + v3.x;
            acc.y += v0.y + v1.y + v2.y + v3.y;
            acc.z += v0.z + v1.z + v2.z + v3.z;
            acc.w += v0.w + v1.w + v2.w + v3.w;
        }
    }
    for (; j < r1; ++j) {
        int s = csr[j];
        float4 v = *reinterpret_cast<const float4*>(g + (size_t)s * FEAT + sub * 4);
        float w = SCALE_SRC ? dinv[s] : 1.0f;
        acc.x += w * v.x; acc.y += w * v.y; acc.z += w * v.z; acc.w += w * v.w;
    }

    const float4 bb = *reinterpret_cast<const float4*>(b + sub * 4);
    float4 o;
    o.x = dv * acc.x + bb.x;
    o.y = dv * acc.y + bb.y;
    o.z = dv * acc.z + bb.z;
    o.w = dv * acc.w + bb.w;
    if (ELU) {
        o.x = o.x > 0.f ? o.x : expm1f(o.x);
        o.y = o.y > 0.f ? o.y : expm1f(o.y);
        o.z = o.z > 0.f ? o.z : expm1f(o.z);
        o.w = o.w > 0.f ? o.w : expm1f(o.w);
    }
    *reinterpret_cast<float4*>(out + (size_t)node * FEAT + sub * 4) = o;
}

extern "C" void kernel_launch(void* const* d_in, const int* in_sizes, int n_in,
                              void* d_out, int out_size, void* d_ws, size_t ws_size,
                              hipStream_t stream) {
    const float* x  = (const float*)d_in[0];
    const float* W1 = (const float*)d_in[1];
    const float* b1 = (const float*)d_in[2];
    const float* W2 = (const float*)d_in[3];
    const float* b2 = (const float*)d_in[4];
    const float* W3 = (const float*)d_in[5];
    const float* b3 = (const float*)d_in[6];
    const int*   ei = (const int*)d_in[7];     // int32 (JAX x64-disabled)

    const int N  = in_sizes[0] / 64;           // 80000
    const int E  = in_sizes[7] / 2;            // 1280000
    const int* src = ei;
    const int* dst = ei + E;

    auto cdiv = [](long long a, long long b) { return (int)((a + b - 1) / b); };
    const int NB = cdiv(N, 256);               // scan blocks (313)

    // workspace layout
    float* ws = (float*)d_ws;
    float* dinv = ws;                           // [N]
    float* A    = dinv + N;                     // [N*64]  h/g buffer
    float* C    = A + (size_t)N * 64;           // [N*64]  layer output
    int* cnt4      = (int*)(C + (size_t)N * 64);// [4*N]  sharded histogram
    int4* base4    = (int4*)(cnt4 + 4 * (size_t)N); // [N]
    int* row_start = (int*)(base4 + N);         // [N+1]
    int* csr       = row_start + N + 1;         // [E]
    int* bsum      = csr + E;                   // [NB]
    int* boff      = bsum + NB;                 // [NB]
    int* rankp     = (int*)C;                   // [E] aliases C (dead until agg1)
    float* out = (float*)d_out;                 // [N*32]

    // --- CSR build (hist fused with GEMM1) ---
    hipMemsetAsync(cnt4, 0, sizeof(int) * 4 * (size_t)N, stream);
    const int histBlocks = cdiv(E, 1024);       // 1250
    const int gemmBlocks = cdiv(N, 64);         // 1250
    // interleaved: odd = hist, even = gemm1 (h1 = x@W1 unscaled -> A)
    k_hist_gemm1<<<histBlocks + gemmBlocks, 256, 0, stream>>>(
        dst, E, N, cnt4, rankp, x, W1, A, N);
    k_scan1<<<NB, 256, 0, stream>>>(cnt4, N, bsum);
    k_scan2<<<1, 512, 0, stream>>>(bsum, NB, boff, row_start, N);
    k_scan3<<<NB, 256, 0, stream>>>(cnt4, N, boff, row_start, base4, dinv);
    k_fill_csr<<<cdiv(E, 1024), 256, 0, stream>>>(src, dst, rankp, base4, E, csr);

    // --- layer 1: A (unscaled h1) -> C, dinv applied per-edge ---
    k_aggregate<64, true, true><<<cdiv(N, 16), 256, 0, stream>>>(
        A, row_start, csr, dinv, b1, C, N);

    // --- layer 2: C -> C (A as scaled g) ---
    k_gemm_scale<64><<<cdiv(N, 64), 256, 0, stream>>>(C, W2, dinv, A, N);
    k_aggregate<64, true, false><<<cdiv(N, 16), 256, 0, stream>>>(
        A, row_start, csr, dinv, b2, C, N);

    // --- layer 3: C -> d_out ---
    k_gemm_scale<32><<<cdiv(N, 128), 256, 0, stream>>>(C, W3, dinv, A, N);
    k_aggregate<32, false, false><<<cdiv(N, 32), 256, 0, stream>>>(
        A, row_start, csr, dinv, b3, out, N);
}

// Round 11
// 292.629 us; speedup vs baseline: 1.1227x; 1.0692x over previous
//
#include <hip/hip_runtime.h>
#include <cmath>

// ---------------------------------------------------------------------------
// GCN 3-layer forward, MI355X — CSR-pull; hist∥GEMM1 fused; agg+GEMM fused.
//   h1 = x@W1 (unscaled, fused with hist)
//   layer1: out1 = elu(dinv*(sum dinv[s]h1[s] + dinv[d]h1[d]) + b1); g2 = (out1@W2)*dinv   [one kernel]
//   layer2: out2 = elu(dinv*(sum g2[s] + g2[d]) + b2);               g3 = (out2@W3)*dinv   [one kernel]
//   layer3: out  = dinv*(sum g3[s] + g3[d]) + b3                                           [plain agg]
// Returning-atomic ceiling (~22G/s, R8/R9) -> hist hidden under GEMM1 (R10).
// ---------------------------------------------------------------------------

// ---- fused: odd blocks = sharded histogram, even blocks = GEMM1 (unscaled) --
__global__ __launch_bounds__(256) void k_hist_gemm1(
    const int* __restrict__ dst, int nE, int nN,
    int* __restrict__ cnt4, int* __restrict__ rankp,
    const float* __restrict__ x, const float* __restrict__ W,
    float* __restrict__ h, int n) {
    constexpr int OUT = 64;
    constexpr int CG = OUT / 4;
    constexpr int RG = 256 / CG;
    constexpr int ROWS = RG * 4;       // 64 rows/block
    constexpr int XLD = 68;
    __shared__ float Ws[64 * OUT];
    __shared__ float xs[ROWS * XLD];

    const int tid = threadIdx.x;

    if (blockIdx.x & 1) {
        const int bid = blockIdx.x >> 1;
        const int t = bid * 256 + tid;
        const int e0 = t * 4;
        const int sh = (tid >> 6) & 3;                 // per-wave shard
        int* __restrict__ mycnt = cnt4 + (size_t)sh * nN;
        if (e0 + 4 <= nE) {
            int4 d = *reinterpret_cast<const int4*>(dst + e0);
            int r0 = atomicAdd(&mycnt[d.x], 1);
            int r1 = atomicAdd(&mycnt[d.y], 1);
            int r2 = atomicAdd(&mycnt[d.z], 1);
            int r3 = atomicAdd(&mycnt[d.w], 1);
            *reinterpret_cast<int4*>(rankp + e0) =
                make_int4(r0 | (sh << 28), r1 | (sh << 28),
                          r2 | (sh << 28), r3 | (sh << 28));
        } else {
            for (int e = e0; e < nE; ++e)
                rankp[e] = atomicAdd(&mycnt[dst[e]], 1) | (sh << 28);
        }
        return;
    }

    const int bid = blockIdx.x >> 1;
    const int row0 = bid * ROWS;

#pragma unroll
    for (int i = tid * 4; i < 64 * OUT; i += 1024)
        *reinterpret_cast<float4*>(&Ws[i]) =
            *reinterpret_cast<const float4*>(&W[i]);

#pragma unroll
    for (int it = 0; it < ROWS / 16; ++it) {
        const int flat = it * 1024 + tid * 4;
        const int r = flat >> 6;
        const int k = flat & 63;
        float4 v;
        if (row0 + r < n)
            v = *reinterpret_cast<const float4*>(x + (size_t)(row0 + r) * 64 + k);
        else
            v = make_float4(0.f, 0.f, 0.f, 0.f);
        *reinterpret_cast<float4*>(&xs[r * XLD + k]) = v;
    }
    __syncthreads();

    const int rg = tid / CG;
    const int cg = tid % CG;
    const int r0 = rg * 4;

    float4 acc[4];
#pragma unroll
    for (int i = 0; i < 4; ++i) acc[i] = make_float4(0.f, 0.f, 0.f, 0.f);

#pragma unroll 2
    for (int kc = 0; kc < 16; ++kc) {
        float4 xr[4], wk[4];
#pragma unroll
        for (int i = 0; i < 4; ++i)
            xr[i] = *reinterpret_cast<const float4*>(&xs[(r0 + i) * XLD + kc * 4]);
#pragma unroll
        for (int kk = 0; kk < 4; ++kk)
            wk[kk] = *reinterpret_cast<const float4*>(&Ws[(kc * 4 + kk) * OUT + cg * 4]);
#pragma unroll
        for (int kk = 0; kk < 4; ++kk) {
#pragma unroll
            for (int i = 0; i < 4; ++i) {
                const float xv = (kk == 0) ? xr[i].x
                               : (kk == 1) ? xr[i].y
                               : (kk == 2) ? xr[i].z
                                           : xr[i].w;
                acc[i].x += xv * wk[kk].x;
                acc[i].y += xv * wk[kk].y;
                acc[i].z += xv * wk[kk].z;
                acc[i].w += xv * wk[kk].w;
            }
        }
    }

#pragma unroll
    for (int i = 0; i < 4; ++i) {
        const int row = row0 + r0 + i;
        if (row < n)
            *reinterpret_cast<float4*>(h + (size_t)row * OUT + cg * 4) = acc[i];
    }
}

// scan level 1: per-block (256-wide) sums over all 4 shards
__global__ __launch_bounds__(256) void k_scan1(const int* __restrict__ cnt4, int n,
                                               int* __restrict__ bsum) {
    __shared__ int s[256];
    int i = blockIdx.x * 256 + threadIdx.x;
    int v = 0;
    if (i < n)
        v = cnt4[i] + cnt4[n + i] + cnt4[2 * n + i] + cnt4[3 * n + i];
    s[threadIdx.x] = v;
    __syncthreads();
    for (int off = 128; off > 0; off >>= 1) {
        if (threadIdx.x < off) s[threadIdx.x] += s[threadIdx.x + off];
        __syncthreads();
    }
    if (threadIdx.x == 0) bsum[blockIdx.x] = s[0];
}

// scan level 3 (scan2 folded in): each block sums bsum[0..bid) itself, then
// per-block exclusive scan; writes row_start, base4, dinv, and row_start[n].
__global__ __launch_bounds__(256) void k_scan3(const int* __restrict__ cnt4, int n,
                                               const int* __restrict__ bsum,
                                               int* __restrict__ row_start,
                                               int4* __restrict__ base4,
                                               float* __restrict__ dinv) {
    __shared__ int red[256];
    __shared__ int s[256];
    const int bid = blockIdx.x;
    int part = 0;
    for (int i = threadIdx.x; i < bid; i += 256) part += bsum[i];
    red[threadIdx.x] = part;
    __syncthreads();
    for (int off = 128; off > 0; off >>= 1) {
        if (threadIdx.x < off) red[threadIdx.x] += red[threadIdx.x + off];
        __syncthreads();
    }
    const int boff = red[0];

    int i = bid * 256 + threadIdx.x;
    int c0 = 0, c1 = 0, c2 = 0, c3 = 0;
    if (i < n) {
        c0 = cnt4[i];
        c1 = cnt4[n + i];
        c2 = cnt4[2 * n + i];
        c3 = cnt4[3 * n + i];
    }
    const int v = c0 + c1 + c2 + c3;
    s[threadIdx.x] = v;
    __syncthreads();
    for (int off = 1; off < 256; off <<= 1) {
        int t = (threadIdx.x >= off) ? s[threadIdx.x - off] : 0;
        __syncthreads();
        s[threadIdx.x] += t;
        __syncthreads();
    }
    if (i < n) {
        const int ex = boff + s[threadIdx.x] - v;
        row_start[i] = ex;
        base4[i] = make_int4(ex, ex + c0, ex + c0 + c1, ex + c0 + c1 + c2);
        dinv[i] = rsqrtf((float)v + 1.0f);  // +1 self-loop
        if (i == n - 1) row_start[n] = ex + v;
    }
}

// atomic-free CSR fill: slot = base4[dst][shard] + local_rank; 4 edges/thread
__global__ __launch_bounds__(256) void k_fill_csr(
    const int* __restrict__ src, const int* __restrict__ dst,
    const int* __restrict__ rankp, const int4* __restrict__ base4,
    int nE, int* __restrict__ csr) {
    const int t = blockIdx.x * 256 + threadIdx.x;
    const int e0 = t * 4;
    if (e0 + 4 <= nE) {
        int4 d = *reinterpret_cast<const int4*>(dst + e0);
        int4 s = *reinterpret_cast<const int4*>(src + e0);
        int4 rp = *reinterpret_cast<const int4*>(rankp + e0);
        int4 b0 = base4[d.x];
        int4 b1 = base4[d.y];
        int4 b2 = base4[d.z];
        int4 b3 = base4[d.w];
        auto pick = [](const int4& b, int sh) {
            return sh == 0 ? b.x : sh == 1 ? b.y : sh == 2 ? b.z : b.w;
        };
        csr[pick(b0, rp.x >> 28) + (rp.x & 0x0FFFFFFF)] = s.x;
        csr[pick(b1, rp.y >> 28) + (rp.y & 0x0FFFFFFF)] = s.y;
        csr[pick(b2, rp.z >> 28) + (rp.z & 0x0FFFFFFF)] = s.z;
        csr[pick(b3, rp.w >> 28) + (rp.w & 0x0FFFFFFF)] = s.w;
    } else {
        for (int e = e0; e < nE; ++e) {
            int rp = rankp[e];
            int4 b = base4[dst[e]];
            int sh = rp >> 28;
            int base = sh == 0 ? b.x : sh == 1 ? b.y : sh == 2 ? b.z : b.w;
            csr[base + (rp & 0x0FFFFFFF)] = src[e];
        }
    }
}

// ---- fused aggregate (FEAT=64 in) + elu + GEMM (64 x OUTW) + dinv scale ----
// 16 nodes/block; agg phase: 16 threads/node (float4). Result -> LDS hs,
// then in-block GEMM vs W (LDS) writes gout = (out @ W) * dinv[row].
template <bool SCALE_SRC, int OUTW>
__global__ __launch_bounds__(256) void k_agg_gemm(
    const float* __restrict__ g, const int* __restrict__ row_start,
    const int* __restrict__ csr, const float* __restrict__ dinv,
    const float* __restrict__ b, const float* __restrict__ W,
    float* __restrict__ gout, int n) {
    constexpr int TPN = 16, NPB = 16;
    __shared__ float Ws[64 * OUTW];
    __shared__ float hs[NPB][68];

    const int tid = threadIdx.x;
    // stage W (once per block)
#pragma unroll
    for (int i = tid * 4; i < 64 * OUTW; i += 1024)
        *reinterpret_cast<float4*>(&Ws[i]) =
            *reinterpret_cast<const float4*>(&W[i]);

    const int node = blockIdx.x * NPB + tid / TPN;
    const int sub = tid % TPN;
    const bool valid = node < n;

    float4 o = make_float4(0.f, 0.f, 0.f, 0.f);
    float dv = 0.f;
    if (valid) {
        const int r0 = row_start[node];
        const int r1 = row_start[node + 1];
        dv = dinv[node];
        float4 acc = *reinterpret_cast<const float4*>(g + (size_t)node * 64 + sub * 4);
        if (SCALE_SRC) { acc.x *= dv; acc.y *= dv; acc.z *= dv; acc.w *= dv; }
        int j = r0;
        for (; j + 4 <= r1; j += 4) {
            int s0 = csr[j], s1 = csr[j + 1], s2 = csr[j + 2], s3 = csr[j + 3];
            float4 v0 = *reinterpret_cast<const float4*>(g + (size_t)s0 * 64 + sub * 4);
            float4 v1 = *reinterpret_cast<const float4*>(g + (size_t)s1 * 64 + sub * 4);
            float4 v2 = *reinterpret_cast<const float4*>(g + (size_t)s2 * 64 + sub * 4);
            float4 v3 = *reinterpret_cast<const float4*>(g + (size_t)s3 * 64 + sub * 4);
            if (SCALE_SRC) {
                float w0 = dinv[s0], w1 = dinv[s1], w2 = dinv[s2], w3 = dinv[s3];
                acc.x += w0 * v0.x + w1 * v1.x + w2 * v2.x + w3 * v3.x;
                acc.y += w0 * v0.y + w1 * v1.y + w2 * v2.y + w3 * v3.y;
                acc.z += w0 * v0.z + w1 * v1.z + w2 * v2.z + w3 * v3.z;
                acc.w += w0 * v0.w + w1 * v1.w + w2 * v2.w + w3 * v3.w;
            } else {
                acc.x += v0.x + v1.x + v2.x + v3.x;
                acc.y += v0.y + v1.y + v2.y + v3.y;
                acc.z += v0.z + v1.z + v2.z + v3.z;
                acc.w += v0.w + v1.w + v2.w + v3.w;
            }
        }
        for (; j < r1; ++j) {
            int s = csr[j];
            float4 v = *reinterpret_cast<const float4*>(g + (size_t)s * 64 + sub * 4);
            float w = SCALE_SRC ? dinv[s] : 1.0f;
            acc.x += w * v.x; acc.y += w * v.y; acc.z += w * v.z; acc.w += w * v.w;
        }
        const float4 bb = *reinterpret_cast<const float4*>(b + sub * 4);
        o.x = dv * acc.x + bb.x;
        o.y = dv * acc.y + bb.y;
        o.z = dv * acc.z + bb.z;
        o.w = dv * acc.w + bb.w;
        // ELU (layers 1 and 2 are always ELU)
        o.x = o.x > 0.f ? o.x : expm1f(o.x);
        o.y = o.y > 0.f ? o.y : expm1f(o.y);
        o.z = o.z > 0.f ? o.z : expm1f(o.z);
        o.w = o.w > 0.f ? o.w : expm1f(o.w);
    }
    *reinterpret_cast<float4*>(&hs[tid / TPN][sub * 4]) = o;
    __syncthreads();

    // GEMM: [NPB x 64] @ [64 x OUTW] -> gout rows * dinv
    constexpr int CG2 = OUTW / 4;            // 16 (OUTW=64) / 8 (OUTW=32)
    if (tid < NPB * CG2) {
        const int n2 = tid / CG2;
        const int cg2 = tid % CG2;
        float4 a2 = make_float4(0.f, 0.f, 0.f, 0.f);
#pragma unroll
        for (int k4 = 0; k4 < 16; ++k4) {
            float4 h4 = *reinterpret_cast<const float4*>(&hs[n2][k4 * 4]);
            float4 w0 = *reinterpret_cast<const float4*>(&Ws[(k4 * 4 + 0) * OUTW + cg2 * 4]);
            float4 w1 = *reinterpret_cast<const float4*>(&Ws[(k4 * 4 + 1) * OUTW + cg2 * 4]);
            float4 w2 = *reinterpret_cast<const float4*>(&Ws[(k4 * 4 + 2) * OUTW + cg2 * 4]);
            float4 w3 = *reinterpret_cast<const float4*>(&Ws[(k4 * 4 + 3) * OUTW + cg2 * 4]);
            a2.x += h4.x * w0.x + h4.y * w1.x + h4.z * w2.x + h4.w * w3.x;
            a2.y += h4.x * w0.y + h4.y * w1.y + h4.z * w2.y + h4.w * w3.y;
            a2.z += h4.x * w0.z + h4.y * w1.z + h4.z * w2.z + h4.w * w3.z;
            a2.w += h4.x * w0.w + h4.y * w1.w + h4.z * w2.w + h4.w * w3.w;
        }
        const int gn = blockIdx.x * NPB + n2;
        if (gn < n) {
            const float dv2 = dinv[gn];
            a2.x *= dv2; a2.y *= dv2; a2.z *= dv2; a2.w *= dv2;
            *reinterpret_cast<float4*>(gout + (size_t)gn * OUTW + cg2 * 4) = a2;
        }
    }
}

// Plain pull-aggregate + finalize (layer 3, FEAT=32, no ELU).
template <int FEAT, bool ELU>
__global__ __launch_bounds__(256) void k_aggregate(
    const float* __restrict__ g, const int* __restrict__ row_start,
    const int* __restrict__ csr, const float* __restrict__ dinv,
    const float* __restrict__ b, float* __restrict__ out, int n) {
    constexpr int TPN = FEAT / 4;
    constexpr int NPB = 256 / TPN;
    const int tid = threadIdx.x;
    const int node = blockIdx.x * NPB + tid / TPN;
    const int sub = tid % TPN;
    if (node >= n) return;

    const int r0 = row_start[node];
    const int r1 = row_start[node + 1];
    float4 acc = *reinterpret_cast<const float4*>(g + (size_t)node * FEAT + sub * 4);

    int j = r0;
    for (; j + 4 <= r1; j += 4) {
        int s0 = csr[j], s1 = csr[j + 1], s2 = csr[j + 2], s3 = csr[j + 3];
        float4 v0 = *reinterpret_cast<const float4*>(g + (size_t)s0 * FEAT + sub * 4);
        float4 v1 = *reinterpret_cast<const float4*>(g + (size_t)s1 * FEAT + sub * 4);
        float4 v2 = *reinterpret_cast<const float4*>(g + (size_t)s2 * FEAT + sub * 4);
        float4 v3 = *reinterpret_cast<const float4*>(g + (size_t)s3 * FEAT + sub * 4);
        acc.x += v0.x + v1.x + v2.x + v3.x;
        acc.y += v0.y + v1.y + v2.y + v3.y;
        acc.z += v0.z + v1.z + v2.z + v3.z;
        acc.w += v0.w + v1.w + v2.w + v3.w;
    }
    for (; j < r1; ++j) {
        int s = csr[j];
        float4 v = *reinterpret_cast<const float4*>(g + (size_t)s * FEAT + sub * 4);
        acc.x += v.x; acc.y += v.y; acc.z += v.z; acc.w += v.w;
    }

    const float dv = dinv[node];
    const float4 bb = *reinterpret_cast<const float4*>(b + sub * 4);
    float4 o;
    o.x = dv * acc.x + bb.x;
    o.y = dv * acc.y + bb.y;
    o.z = dv * acc.z + bb.z;
    o.w = dv * acc.w + bb.w;
    if (ELU) {
        o.x = o.x > 0.f ? o.x : expm1f(o.x);
        o.y = o.y > 0.f ? o.y : expm1f(o.y);
        o.z = o.z > 0.f ? o.z : expm1f(o.z);
        o.w = o.w > 0.f ? o.w : expm1f(o.w);
    }
    *reinterpret_cast<float4*>(out + (size_t)node * FEAT + sub * 4) = o;
}

extern "C" void kernel_launch(void* const* d_in, const int* in_sizes, int n_in,
                              void* d_out, int out_size, void* d_ws, size_t ws_size,
                              hipStream_t stream) {
    const float* x  = (const float*)d_in[0];
    const float* W1 = (const float*)d_in[1];
    const float* b1 = (const float*)d_in[2];
    const float* W2 = (const float*)d_in[3];
    const float* b2 = (const float*)d_in[4];
    const float* W3 = (const float*)d_in[5];
    const float* b3 = (const float*)d_in[6];
    const int*   ei = (const int*)d_in[7];     // int32 (JAX x64-disabled)

    const int N  = in_sizes[0] / 64;           // 80000
    const int E  = in_sizes[7] / 2;            // 1280000
    const int* src = ei;
    const int* dst = ei + E;

    auto cdiv = [](long long a, long long b) { return (int)((a + b - 1) / b); };
    const int NB = cdiv(N, 256);               // scan blocks (313)

    // workspace layout
    float* ws = (float*)d_ws;
    float* dinv = ws;                           // [N]
    float* A    = dinv + N;                     // [N*64]  h1 / g3 buffer
    float* C    = A + (size_t)N * 64;           // [N*64]  g2 buffer
    int* cnt4      = (int*)(C + (size_t)N * 64);// [4*N]  sharded histogram
    int4* base4    = (int4*)(cnt4 + 4 * (size_t)N); // [N]
    int* row_start = (int*)(base4 + N);         // [N+1]
    int* csr       = row_start + N + 1;         // [E]
    int* bsum      = csr + E;                   // [NB]
    int* rankp     = (int*)C;                   // [E] aliases C (dead after fill)
    float* out = (float*)d_out;                 // [N*32]

    // --- CSR build (hist fused with GEMM1) ---
    hipMemsetAsync(cnt4, 0, sizeof(int) * 4 * (size_t)N, stream);
    const int histBlocks = cdiv(E, 1024);       // 1250
    const int gemmBlocks = cdiv(N, 64);         // 1250 (must equal histBlocks split)
    k_hist_gemm1<<<histBlocks + gemmBlocks, 256, 0, stream>>>(
        dst, E, N, cnt4, rankp, x, W1, A, N);
    k_scan1<<<NB, 256, 0, stream>>>(cnt4, N, bsum);
    k_scan3<<<NB, 256, 0, stream>>>(cnt4, N, bsum, row_start, base4, dinv);
    k_fill_csr<<<cdiv(E, 1024), 256, 0, stream>>>(src, dst, rankp, base4, E, csr);

    // --- layer 1 (+GEMM2): A (unscaled h1) -> C (scaled g2) ---
    k_agg_gemm<true, 64><<<cdiv(N, 16), 256, 0, stream>>>(
        A, row_start, csr, dinv, b1, W2, C, N);

    // --- layer 2 (+GEMM3): C (g2) -> A (scaled g3, 32-wide) ---
    k_agg_gemm<false, 32><<<cdiv(N, 16), 256, 0, stream>>>(
        C, row_start, csr, dinv, b2, W3, A, N);

    // --- layer 3: A (g3) -> d_out ---
    k_aggregate<32, false><<<cdiv(N, 32), 256, 0, stream>>>(
        A, row_start, csr, dinv, b3, out, N);
}

// Round 14
// 247.202 us; speedup vs baseline: 1.3290x; 1.1838x over previous
//
#include <hip/hip_runtime.h>
#include <hip/hip_fp16.h>
#include <cmath>

// ---------------------------------------------------------------------------
// GCN 3-layer forward, MI355X — CSR-pull; hist∥GEMM1 fused; agg+GEMM fused;
// fp16 intermediate node features (f32 accumulate / weights / output).
//   h1 = x@W1 (half, fused with hist)
//   L1: out1 = elu(dv*(Σ dinv_s h1[s] + dv h1[d]) + b1); g2 = (out1@W2)*dinv  [half]
//   L2: out2 = elu(dv*(Σ g2[s] + g2[d]) + b2);          g3 = (out2@W3)*dinv  [half]
//   L3: out  = dv*(Σ g3[s] + g3[d]) + b3                                     [f32]
// Evidence: returning-atomic ceiling ~22G/s (R8/R9) -> hist hidden under GEMM1
// (R10); agg bound by per-XCD L2 refill (FETCH≈8*|g|*0.88, R11) -> halve bytes.
// (3rd submission of the same source — R12/R13 were infra failures)
// ---------------------------------------------------------------------------

// ---- fused: odd blocks = sharded histogram, even blocks = GEMM1 (h half) ---
__global__ __launch_bounds__(256) void k_hist_gemm1(
    const int* __restrict__ dst, int nE, int nN,
    int* __restrict__ cnt4, int* __restrict__ rankp,
    const float* __restrict__ x, const float* __restrict__ W,
    __half* __restrict__ h, int n) {
    constexpr int OUT = 64;
    constexpr int CG = OUT / 4;
    constexpr int RG = 256 / CG;
    constexpr int ROWS = RG * 4;       // 64 rows/block
    constexpr int XLD = 68;
    __shared__ float Ws[64 * OUT];
    __shared__ float xs[ROWS * XLD];

    const int tid = threadIdx.x;

    if (blockIdx.x & 1) {
        const int bid = blockIdx.x >> 1;
        const int t = bid * 256 + tid;
        const int e0 = t * 4;
        const int sh = (tid >> 6) & 3;                 // per-wave shard
        int* __restrict__ mycnt = cnt4 + (size_t)sh * nN;
        if (e0 + 4 <= nE) {
            int4 d = *reinterpret_cast<const int4*>(dst + e0);
            int r0 = atomicAdd(&mycnt[d.x], 1);
            int r1 = atomicAdd(&mycnt[d.y], 1);
            int r2 = atomicAdd(&mycnt[d.z], 1);
            int r3 = atomicAdd(&mycnt[d.w], 1);
            *reinterpret_cast<int4*>(rankp + e0) =
                make_int4(r0 | (sh << 28), r1 | (sh << 28),
                          r2 | (sh << 28), r3 | (sh << 28));
        } else {
            for (int e = e0; e < nE; ++e)
                rankp[e] = atomicAdd(&mycnt[dst[e]], 1) | (sh << 28);
        }
        return;
    }

    const int bid = blockIdx.x >> 1;
    const int row0 = bid * ROWS;

#pragma unroll
    for (int i = tid * 4; i < 64 * OUT; i += 1024)
        *reinterpret_cast<float4*>(&Ws[i]) =
            *reinterpret_cast<const float4*>(&W[i]);

#pragma unroll
    for (int it = 0; it < ROWS / 16; ++it) {
        const int flat = it * 1024 + tid * 4;
        const int r = flat >> 6;
        const int k = flat & 63;
        float4 v;
        if (row0 + r < n)
            v = *reinterpret_cast<const float4*>(x + (size_t)(row0 + r) * 64 + k);
        else
            v = make_float4(0.f, 0.f, 0.f, 0.f);
        *reinterpret_cast<float4*>(&xs[r * XLD + k]) = v;
    }
    __syncthreads();

    const int rg = tid / CG;
    const int cg = tid % CG;
    const int r0 = rg * 4;

    float4 acc[4];
#pragma unroll
    for (int i = 0; i < 4; ++i) acc[i] = make_float4(0.f, 0.f, 0.f, 0.f);

#pragma unroll 2
    for (int kc = 0; kc < 16; ++kc) {
        float4 xr[4], wk[4];
#pragma unroll
        for (int i = 0; i < 4; ++i)
            xr[i] = *reinterpret_cast<const float4*>(&xs[(r0 + i) * XLD + kc * 4]);
#pragma unroll
        for (int kk = 0; kk < 4; ++kk)
            wk[kk] = *reinterpret_cast<const float4*>(&Ws[(kc * 4 + kk) * OUT + cg * 4]);
#pragma unroll
        for (int kk = 0; kk < 4; ++kk) {
#pragma unroll
            for (int i = 0; i < 4; ++i) {
                const float xv = (kk == 0) ? xr[i].x
                               : (kk == 1) ? xr[i].y
                               : (kk == 2) ? xr[i].z
                                           : xr[i].w;
                acc[i].x += xv * wk[kk].x;
                acc[i].y += xv * wk[kk].y;
                acc[i].z += xv * wk[kk].z;
                acc[i].w += xv * wk[kk].w;
            }
        }
    }

#pragma unroll
    for (int i = 0; i < 4; ++i) {
        const int row = row0 + r0 + i;
        if (row < n) {
            __half2 p0 = __floats2half2_rn(acc[i].x, acc[i].y);
            __half2 p1 = __floats2half2_rn(acc[i].z, acc[i].w);
            uint2 u = make_uint2(*reinterpret_cast<unsigned int*>(&p0),
                                 *reinterpret_cast<unsigned int*>(&p1));
            *reinterpret_cast<uint2*>(h + (size_t)row * 64 + cg * 4) = u;
        }
    }
}

// scan level 1: per-block (256-wide) sums over all 4 shards
__global__ __launch_bounds__(256) void k_scan1(const int* __restrict__ cnt4, int n,
                                               int* __restrict__ bsum) {
    __shared__ int s[256];
    int i = blockIdx.x * 256 + threadIdx.x;
    int v = 0;
    if (i < n)
        v = cnt4[i] + cnt4[n + i] + cnt4[2 * n + i] + cnt4[3 * n + i];
    s[threadIdx.x] = v;
    __syncthreads();
    for (int off = 128; off > 0; off >>= 1) {
        if (threadIdx.x < off) s[threadIdx.x] += s[threadIdx.x + off];
        __syncthreads();
    }
    if (threadIdx.x == 0) bsum[blockIdx.x] = s[0];
}

// scan level 3 (scan2 folded in): block sums bsum[0..bid) itself, then
// per-block exclusive scan; writes row_start, base4, dinv, row_start[n].
__global__ __launch_bounds__(256) void k_scan3(const int* __restrict__ cnt4, int n,
                                               const int* __restrict__ bsum,
                                               int* __restrict__ row_start,
                                               int4* __restrict__ base4,
                                               float* __restrict__ dinv) {
    __shared__ int red[256];
    __shared__ int s[256];
    const int bid = blockIdx.x;
    int part = 0;
    for (int i = threadIdx.x; i < bid; i += 256) part += bsum[i];
    red[threadIdx.x] = part;
    __syncthreads();
    for (int off = 128; off > 0; off >>= 1) {
        if (threadIdx.x < off) red[threadIdx.x] += red[threadIdx.x + off];
        __syncthreads();
    }
    const int boff = red[0];

    int i = bid * 256 + threadIdx.x;
    int c0 = 0, c1 = 0, c2 = 0, c3 = 0;
    if (i < n) {
        c0 = cnt4[i];
        c1 = cnt4[n + i];
        c2 = cnt4[2 * n + i];
        c3 = cnt4[3 * n + i];
    }
    const int v = c0 + c1 + c2 + c3;
    s[threadIdx.x] = v;
    __syncthreads();
    for (int off = 1; off < 256; off <<= 1) {
        int t = (threadIdx.x >= off) ? s[threadIdx.x - off] : 0;
        __syncthreads();
        s[threadIdx.x] += t;
        __syncthreads();
    }
    if (i < n) {
        const int ex = boff + s[threadIdx.x] - v;
        row_start[i] = ex;
        base4[i] = make_int4(ex, ex + c0, ex + c0 + c1, ex + c0 + c1 + c2);
        dinv[i] = rsqrtf((float)v + 1.0f);  // +1 self-loop
        if (i == n - 1) row_start[n] = ex + v;
    }
}

// atomic-free CSR fill: slot = base4[dst][shard] + local_rank; 4 edges/thread
__global__ __launch_bounds__(256) void k_fill_csr(
    const int* __restrict__ src, const int* __restrict__ dst,
    const int* __restrict__ rankp, const int4* __restrict__ base4,
    int nE, int* __restrict__ csr) {
    const int t = blockIdx.x * 256 + threadIdx.x;
    const int e0 = t * 4;
    if (e0 + 4 <= nE) {
        int4 d = *reinterpret_cast<const int4*>(dst + e0);
        int4 s = *reinterpret_cast<const int4*>(src + e0);
        int4 rp = *reinterpret_cast<const int4*>(rankp + e0);
        int4 b0 = base4[d.x];
        int4 b1 = base4[d.y];
        int4 b2 = base4[d.z];
        int4 b3 = base4[d.w];
        auto pick = [](const int4& b, int sh) {
            return sh == 0 ? b.x : sh == 1 ? b.y : sh == 2 ? b.z : b.w;
        };
        csr[pick(b0, rp.x >> 28) + (rp.x & 0x0FFFFFFF)] = s.x;
        csr[pick(b1, rp.y >> 28) + (rp.y & 0x0FFFFFFF)] = s.y;
        csr[pick(b2, rp.z >> 28) + (rp.z & 0x0FFFFFFF)] = s.z;
        csr[pick(b3, rp.w >> 28) + (rp.w & 0x0FFFFFFF)] = s.w;
    } else {
        for (int e = e0; e < nE; ++e) {
            int rp = rankp[e];
            int4 b = base4[dst[e]];
            int sh = rp >> 28;
            int base = sh == 0 ? b.x : sh == 1 ? b.y : sh == 2 ? b.z : b.w;
            csr[base + (rp & 0x0FFFFFFF)] = src[e];
        }
    }
}

// convert 16B of 8 halves -> 8 floats, scaled by w, added into a[8]
__device__ __forceinline__ void add_half8(float* a, const uint4& raw, float w) {
    const __half2* hp = reinterpret_cast<const __half2*>(&raw);
#pragma unroll
    for (int q = 0; q < 4; ++q) {
        float2 f = __half22float2(hp[q]);
        a[q * 2 + 0] += w * f.x;
        a[q * 2 + 1] += w * f.y;
    }
}

// ---- fused aggregate (64 half feats in) + elu + GEMM (64xOUTW) + dinv ------
// 32 nodes/block, 8 threads/node (8 halves each). out half.
template <bool SCALE_SRC, int OUTW>
__global__ __launch_bounds__(256) void k_agg_gemm(
    const __half* __restrict__ g, const int* __restrict__ row_start,
    const int* __restrict__ csr, const float* __restrict__ dinv,
    const float* __restrict__ b, const float* __restrict__ W,
    __half* __restrict__ gout, int n) {
    constexpr int TPN = 8, NPB = 32;
    __shared__ float Ws[64 * OUTW];
    __shared__ float hs[NPB][68];

    const int tid = threadIdx.x;
#pragma unroll
    for (int i = tid * 4; i < 64 * OUTW; i += 1024)
        *reinterpret_cast<float4*>(&Ws[i]) =
            *reinterpret_cast<const float4*>(&W[i]);

    const int nloc = tid / TPN;
    const int sub = tid % TPN;
    const int node = blockIdx.x * NPB + nloc;
    const bool valid = node < n;

    float a[8];
#pragma unroll
    for (int q = 0; q < 8; ++q) a[q] = 0.f;
    float dv = 0.f;

    if (valid) {
        const int r0 = row_start[node];
        const int r1 = row_start[node + 1];
        dv = dinv[node];
        // self term
        {
            uint4 raw = *reinterpret_cast<const uint4*>(g + (size_t)node * 64 + sub * 8);
            add_half8(a, raw, SCALE_SRC ? dv : 1.0f);
        }
        int j = r0;
        for (; j + 4 <= r1; j += 4) {
            int s0 = csr[j], s1 = csr[j + 1], s2 = csr[j + 2], s3 = csr[j + 3];
            uint4 v0 = *reinterpret_cast<const uint4*>(g + (size_t)s0 * 64 + sub * 8);
            uint4 v1 = *reinterpret_cast<const uint4*>(g + (size_t)s1 * 64 + sub * 8);
            uint4 v2 = *reinterpret_cast<const uint4*>(g + (size_t)s2 * 64 + sub * 8);
            uint4 v3 = *reinterpret_cast<const uint4*>(g + (size_t)s3 * 64 + sub * 8);
            if (SCALE_SRC) {
                add_half8(a, v0, dinv[s0]);
                add_half8(a, v1, dinv[s1]);
                add_half8(a, v2, dinv[s2]);
                add_half8(a, v3, dinv[s3]);
            } else {
                add_half8(a, v0, 1.0f);
                add_half8(a, v1, 1.0f);
                add_half8(a, v2, 1.0f);
                add_half8(a, v3, 1.0f);
            }
        }
        for (; j < r1; ++j) {
            int s = csr[j];
            uint4 v = *reinterpret_cast<const uint4*>(g + (size_t)s * 64 + sub * 8);
            add_half8(a, v, SCALE_SRC ? dinv[s] : 1.0f);
        }
        // bias + ELU
        float4 bb0 = *reinterpret_cast<const float4*>(b + sub * 8);
        float4 bb1 = *reinterpret_cast<const float4*>(b + sub * 8 + 4);
#pragma unroll
        for (int q = 0; q < 8; ++q) {
            float o = dv * a[q] + ((q < 4) ? (&bb0.x)[q] : (&bb1.x)[q - 4]);
            o = o > 0.f ? o : expm1f(o);
            a[q] = o;
        }
    }
    *reinterpret_cast<float4*>(&hs[nloc][sub * 8]) = make_float4(a[0], a[1], a[2], a[3]);
    *reinterpret_cast<float4*>(&hs[nloc][sub * 8 + 4]) = make_float4(a[4], a[5], a[6], a[7]);
    __syncthreads();

    // GEMM: [NPB x 64] @ [64 x OUTW] -> gout (half) rows * dinv
    constexpr int CG2 = OUTW / 4;          // 16 (OUTW=64) / 8 (OUTW=32)
    for (int t2 = tid; t2 < NPB * CG2; t2 += 256) {
        const int n2 = t2 / CG2;
        const int cg2 = t2 % CG2;
        float4 a2 = make_float4(0.f, 0.f, 0.f, 0.f);
#pragma unroll
        for (int k4 = 0; k4 < 16; ++k4) {
            float4 h4 = *reinterpret_cast<const float4*>(&hs[n2][k4 * 4]);
            float4 w0 = *reinterpret_cast<const float4*>(&Ws[(k4 * 4 + 0) * OUTW + cg2 * 4]);
            float4 w1 = *reinterpret_cast<const float4*>(&Ws[(k4 * 4 + 1) * OUTW + cg2 * 4]);
            float4 w2 = *reinterpret_cast<const float4*>(&Ws[(k4 * 4 + 2) * OUTW + cg2 * 4]);
            float4 w3 = *reinterpret_cast<const float4*>(&Ws[(k4 * 4 + 3) * OUTW + cg2 * 4]);
            a2.x += h4.x * w0.x + h4.y * w1.x + h4.z * w2.x + h4.w * w3.x;
            a2.y += h4.x * w0.y + h4.y * w1.y + h4.z * w2.y + h4.w * w3.y;
            a2.z += h4.x * w0.z + h4.y * w1.z + h4.z * w2.z + h4.w * w3.z;
            a2.w += h4.x * w0.w + h4.y * w1.w + h4.z * w2.w + h4.w * w3.w;
        }
        const int gn = blockIdx.x * NPB + n2;
        if (gn < n) {
            const float dv2 = dinv[gn];
            __half2 p0 = __floats2half2_rn(a2.x * dv2, a2.y * dv2);
            __half2 p1 = __floats2half2_rn(a2.z * dv2, a2.w * dv2);
            uint2 u = make_uint2(*reinterpret_cast<unsigned int*>(&p0),
                                 *reinterpret_cast<unsigned int*>(&p1));
            *reinterpret_cast<uint2*>(gout + (size_t)gn * OUTW + cg2 * 4) = u;
        }
    }
}

// Layer-3 aggregate: 32 half feats in, f32 out, no ELU. 4 threads/node.
__global__ __launch_bounds__(256) void k_aggregate3(
    const __half* __restrict__ g, const int* __restrict__ row_start,
    const int* __restrict__ csr, const float* __restrict__ dinv,
    const float* __restrict__ b, float* __restrict__ out, int n) {
    constexpr int TPN = 4, NPB = 64;
    const int tid = threadIdx.x;
    const int node = blockIdx.x * NPB + tid / TPN;
    const int sub = tid % TPN;
    if (node >= n) return;

    const int r0 = row_start[node];
    const int r1 = row_start[node + 1];
    float a[8];
#pragma unroll
    for (int q = 0; q < 8; ++q) a[q] = 0.f;
    {
        uint4 raw = *reinterpret_cast<const uint4*>(g + (size_t)node * 32 + sub * 8);
        add_half8(a, raw, 1.0f);
    }
    int j = r0;
    for (; j + 4 <= r1; j += 4) {
        int s0 = csr[j], s1 = csr[j + 1], s2 = csr[j + 2], s3 = csr[j + 3];
        uint4 v0 = *reinterpret_cast<const uint4*>(g + (size_t)s0 * 32 + sub * 8);
        uint4 v1 = *reinterpret_cast<const uint4*>(g + (size_t)s1 * 32 + sub * 8);
        uint4 v2 = *reinterpret_cast<const uint4*>(g + (size_t)s2 * 32 + sub * 8);
        uint4 v3 = *reinterpret_cast<const uint4*>(g + (size_t)s3 * 32 + sub * 8);
        add_half8(a, v0, 1.0f);
        add_half8(a, v1, 1.0f);
        add_half8(a, v2, 1.0f);
        add_half8(a, v3, 1.0f);
    }
    for (; j < r1; ++j) {
        int s = csr[j];
        uint4 v = *reinterpret_cast<const uint4*>(g + (size_t)s * 32 + sub * 8);
        add_half8(a, v, 1.0f);
    }

    const float dv = dinv[node];
    float4 bb0 = *reinterpret_cast<const float4*>(b + sub * 8);
    float4 bb1 = *reinterpret_cast<const float4*>(b + sub * 8 + 4);
    float4 o0, o1;
    o0.x = dv * a[0] + bb0.x;
    o0.y = dv * a[1] + bb0.y;
    o0.z = dv * a[2] + bb0.z;
    o0.w = dv * a[3] + bb0.w;
    o1.x = dv * a[4] + bb1.x;
    o1.y = dv * a[5] + bb1.y;
    o1.z = dv * a[6] + bb1.z;
    o1.w = dv * a[7] + bb1.w;
    *reinterpret_cast<float4*>(out + (size_t)node * 32 + sub * 8) = o0;
    *reinterpret_cast<float4*>(out + (size_t)node * 32 + sub * 8 + 4) = o1;
}

extern "C" void kernel_launch(void* const* d_in, const int* in_sizes, int n_in,
                              void* d_out, int out_size, void* d_ws, size_t ws_size,
                              hipStream_t stream) {
    const float* x  = (const float*)d_in[0];
    const float* W1 = (const float*)d_in[1];
    const float* b1 = (const float*)d_in[2];
    const float* W2 = (const float*)d_in[3];
    const float* b2 = (const float*)d_in[4];
    const float* W3 = (const float*)d_in[5];
    const float* b3 = (const float*)d_in[6];
    const int*   ei = (const int*)d_in[7];     // int32 (JAX x64-disabled)

    const int N  = in_sizes[0] / 64;           // 80000
    const int E  = in_sizes[7] / 2;            // 1280000
    const int* src = ei;
    const int* dst = ei + E;

    auto cdiv = [](long long a, long long b) { return (int)((a + b - 1) / b); };
    const int NB = cdiv(N, 256);               // scan blocks (313)

    // workspace layout (element offsets in floats)
    float* ws = (float*)d_ws;
    float* dinv = ws;                           // [N] f32
    __half* A   = (__half*)(dinv + N);          // [N*64] half (h1 / g3)
    __half* C   = (__half*)(dinv + N + (size_t)N * 32); // [N*64] half (g2)
    int* cnt4      = (int*)(dinv + N + (size_t)N * 64); // [4*N]
    int4* base4    = (int4*)(cnt4 + 4 * (size_t)N);     // [N] (16B-aligned)
    int* row_start = (int*)(base4 + N);         // [N+1]
    int* csr       = row_start + N + 1;         // [E]
    int* bsum      = csr + E;                   // [NB]
    int* rankp     = (int*)C;                   // [E] aliases C (dead after fill)
    float* out = (float*)d_out;                 // [N*32] f32

    // --- CSR build (hist fused with GEMM1) ---
    hipMemsetAsync(cnt4, 0, sizeof(int) * 4 * (size_t)N, stream);
    const int histBlocks = cdiv(E, 1024);       // 1250
    const int gemmBlocks = cdiv(N, 64);         // 1250
    k_hist_gemm1<<<histBlocks + gemmBlocks, 256, 0, stream>>>(
        dst, E, N, cnt4, rankp, x, W1, A, N);
    k_scan1<<<NB, 256, 0, stream>>>(cnt4, N, bsum);
    k_scan3<<<NB, 256, 0, stream>>>(cnt4, N, bsum, row_start, base4, dinv);
    k_fill_csr<<<cdiv(E, 1024), 256, 0, stream>>>(src, dst, rankp, base4, E, csr);

    // --- layer 1 (+GEMM2): A (h1) -> C (g2), per-edge dinv ---
    k_agg_gemm<true, 64><<<cdiv(N, 32), 256, 0, stream>>>(
        A, row_start, csr, dinv, b1, W2, C, N);

    // --- layer 2 (+GEMM3): C (g2) -> A (g3, 32-wide) ---
    k_agg_gemm<false, 32><<<cdiv(N, 32), 256, 0, stream>>>(
        C, row_start, csr, dinv, b2, W3, (__half*)A, N);

    // --- layer 3: A (g3) -> d_out (f32) ---
    k_aggregate3<<<cdiv(N, 64), 256, 0, stream>>>(
        (__half*)A, row_start, csr, dinv, b3, out, N);
}